// Round 3
// baseline (54.860 us; speedup 1.0000x reference)
//
#include <hip/hip_runtime.h>
#include <stdint.h>

#define BATCH   32768
#define NBITS   512
#define NWORDS  512          // BATCH / 64
#define NSLICE  16           // K-split: 36 tiles * 16 = 576 blocks (~2.25/CU)
#define SW      32           // words per slice = NWORDS / NSLICE
#define NTILE   36           // 8x8 lower-triangle of 64x64 tiles

typedef unsigned long long u64;

// ---------------------------------------------------------------------------
// Pass 1: bit-pack + build f64 log table.
// packed[w*NBITS + col] = 64-bit mask of rows w*64..w*64+63 for column col.
// ---------------------------------------------------------------------------
__global__ __launch_bounds__(256) void pack_kernel(const float* __restrict__ bits,
                                                   u64* __restrict__ packed,
                                                   double* __restrict__ lg) {
    const int gid = blockIdx.x * 256 + threadIdx.x;   // 0..65535

    // f64 log table for the MI epilogue (args are integers 0..32768)
    if (gid <= BATCH) lg[gid] = (gid > 0) ? log((double)gid) : 0.0;

    const int wv   = threadIdx.x >> 6;
    const int lane = threadIdx.x & 63;
    const int gw   = blockIdx.x * 4 + wv;     // 0..1023
    const int cg   = gw & 1;                  // column half (0..1)
    const int w    = gw >> 1;                 // word 0..511
    const int c0   = cg * 256 + lane * 4;

    u64 m0 = 0, m1 = 0, m2 = 0, m3 = 0;
    const float* base = bits + (size_t)w * 64 * NBITS + c0;
#pragma unroll 16
    for (int r = 0; r < 64; ++r) {
        float4 v = *reinterpret_cast<const float4*>(base + (size_t)r * NBITS);
        const u64 b = 1ull << r;
        if (v.x > 0.0f) m0 |= b;
        if (v.y > 0.0f) m1 |= b;
        if (v.z > 0.0f) m2 |= b;
        if (v.w > 0.0f) m3 |= b;
    }
    u64* dst = packed + (size_t)w * NBITS + c0;
    dst[0] = m0; dst[1] = m1; dst[2] = m2; dst[3] = m3;
}

// ---------------------------------------------------------------------------
// Pass 2: partial Gram. Block = (tile t, slice s); Cp[s][i*512+j] =
// popcount over words [s*32, s*32+32). 64x64 tile, 4x4 register tile with
// interleaved columns {2t,2t+1,2t+32,2t+33} (bank-friendly b128 reads).
// Plain stores -> no atomics, no zero-init needed.
// ---------------------------------------------------------------------------
__global__ __launch_bounds__(256) void gram_kernel(const u64* __restrict__ packed,
                                                   int* __restrict__ Cp) {
    __shared__ u64 ldsI[SW][64];
    __shared__ u64 ldsJ[SW][64];

    const int s = blockIdx.x & (NSLICE - 1);  // K-slice 0..15
    const int t = blockIdx.x >> 4;            // tile 0..35
    int bi = (int)((sqrtf(8.0f * (float)t + 1.0f) - 1.0f) * 0.5f);
    while ((bi + 1) * (bi + 2) / 2 <= t) ++bi;
    while (bi * (bi + 1) / 2 > t) --bi;
    const int bj = t - bi * (bi + 1) / 2;

    const int i0 = bi * 64, j0 = bj * 64;
    const int w0 = s * SW;
    const bool diag = (bi == bj);

    // stage this slice's 32 words x 64 cols for each side
    for (int q = threadIdx.x; q < SW * 32; q += 256) {
        const int wo = q >> 5, cp = (q & 31) * 2;
        const size_t g = (size_t)(w0 + wo) * NBITS;
        *reinterpret_cast<ulonglong2*>(&ldsI[wo][cp]) =
            *reinterpret_cast<const ulonglong2*>(&packed[g + i0 + cp]);
        if (!diag)
            *reinterpret_cast<ulonglong2*>(&ldsJ[wo][cp]) =
                *reinterpret_cast<const ulonglong2*>(&packed[g + j0 + cp]);
    }
    __syncthreads();

    const int ti2 = (threadIdx.x & 15) * 2;   // i-col base (even)
    const int tj2 = (threadIdx.x >> 4) * 2;   // j-col base (even)
    const u64 (*BJ)[64] = diag ? ldsI : ldsJ;

    int acc[4][4] = {};
#pragma unroll 4
    for (int w = 0; w < SW; ++w) {
        const u64 a0 = ldsI[w][ti2],      a1 = ldsI[w][ti2 + 1];
        const u64 a2 = ldsI[w][ti2 + 32], a3 = ldsI[w][ti2 + 33];
        const u64 b0 = BJ[w][tj2],        b1 = BJ[w][tj2 + 1];
        const u64 b2 = BJ[w][tj2 + 32],   b3 = BJ[w][tj2 + 33];
        acc[0][0] += __popcll(a0 & b0); acc[0][1] += __popcll(a0 & b1);
        acc[0][2] += __popcll(a0 & b2); acc[0][3] += __popcll(a0 & b3);
        acc[1][0] += __popcll(a1 & b0); acc[1][1] += __popcll(a1 & b1);
        acc[1][2] += __popcll(a1 & b2); acc[1][3] += __popcll(a1 & b3);
        acc[2][0] += __popcll(a2 & b0); acc[2][1] += __popcll(a2 & b1);
        acc[2][2] += __popcll(a2 & b2); acc[2][3] += __popcll(a2 & b3);
        acc[3][0] += __popcll(a3 & b0); acc[3][1] += __popcll(a3 & b1);
        acc[3][2] += __popcll(a3 & b2); acc[3][3] += __popcll(a3 & b3);
    }

    int* out = Cp + (size_t)s * NBITS * NBITS;
    const int ic[4] = {i0 + ti2, i0 + ti2 + 1, i0 + ti2 + 32, i0 + ti2 + 33};
    const int jc[4] = {j0 + tj2, j0 + tj2 + 1, j0 + tj2 + 32, j0 + tj2 + 33};
#pragma unroll
    for (int a = 0; a < 4; ++a)
#pragma unroll
        for (int b = 0; b < 4; ++b)
            out[(size_t)ic[a] * NBITS + jc[b]] = acc[a][b];
}

// ---------------------------------------------------------------------------
// Pass 3: per-pair MI terms. i = blockIdx.x, j = threadIdx.x (+256).
// Sums the 16 slice partials, then the log-table epilogue (exact integers).
// Deterministic block reduction -> per-block partials.
// ---------------------------------------------------------------------------
__global__ __launch_bounds__(256) void mi_kernel(const int* __restrict__ Cp,
                                                 const double* __restrict__ lg,
                                                 double* __restrict__ bsum,
                                                 int* __restrict__ bcnt) {
    const double invB = 1.0 / (double)BATCH;
    const int i = blockIdx.x;
    double lsum = 0.0;
    int lcnt = 0;

    int ci = 0;
#pragma unroll
    for (int s = 0; s < NSLICE; ++s)
        ci += Cp[(size_t)s * NBITS * NBITS + (size_t)i * NBITS + i];

#pragma unroll
    for (int half = 0; half < 2; ++half) {
        const int j = half * 256 + threadIdx.x;
        if (j < i) {
            int n11 = 0, cj = 0;
#pragma unroll
            for (int s = 0; s < NSLICE; ++s) {
                const int* base = Cp + (size_t)s * NBITS * NBITS;
                n11 += base[(size_t)i * NBITS + j];
                cj  += base[(size_t)j * NBITS + j];
            }

            const int pim[2] = {BATCH - ci, ci};
            const int pjn[2] = {BATCH - cj, cj};
            const int nmn[2][2] = {{BATCH - ci - cj + n11, cj - n11},
                                   {ci - n11, n11}};
            const double lgB = lg[BATCH];
#pragma unroll
            for (int m = 0; m < 2; ++m)
#pragma unroll
                for (int n = 0; n < 2; ++n) {
                    const int c_mn = nmn[m][n];
                    if (c_mn > 0 && pim[m] > 0 && pjn[n] > 0) {
                        lsum += (double)c_mn * invB *
                                (lg[c_mn] + lgB - lg[pim[m]] - lg[pjn[n]]);
                        ++lcnt;
                    }
                }
        }
    }

    __shared__ double ssum[256];
    __shared__ int scnt[256];
    ssum[threadIdx.x] = lsum;
    scnt[threadIdx.x] = lcnt;
    __syncthreads();
    for (int off = 128; off > 0; off >>= 1) {
        if (threadIdx.x < off) {
            ssum[threadIdx.x] += ssum[threadIdx.x + off];
            scnt[threadIdx.x] += scnt[threadIdx.x + off];
        }
        __syncthreads();
    }
    if (threadIdx.x == 0) { bsum[blockIdx.x] = ssum[0]; bcnt[blockIdx.x] = scnt[0]; }
}

// ---------------------------------------------------------------------------
// Pass 4: final deterministic reduce, out = sum / cnt.
// ---------------------------------------------------------------------------
__global__ __launch_bounds__(256) void final_kernel(const double* __restrict__ bsum,
                                                    const int* __restrict__ bcnt,
                                                    float* __restrict__ out,
                                                    int nblocks) {
    __shared__ double ssum[256];
    __shared__ int scnt[256];
    double s = 0.0; int c = 0;
    for (int k = threadIdx.x; k < nblocks; k += 256) { s += bsum[k]; c += bcnt[k]; }
    ssum[threadIdx.x] = s;
    scnt[threadIdx.x] = c;
    __syncthreads();
    for (int off = 128; off > 0; off >>= 1) {
        if (threadIdx.x < off) {
            ssum[threadIdx.x] += ssum[threadIdx.x + off];
            scnt[threadIdx.x] += scnt[threadIdx.x + off];
        }
        __syncthreads();
    }
    if (threadIdx.x == 0) out[0] = (float)(ssum[0] / (double)scnt[0]);
}

// ---------------------------------------------------------------------------
extern "C" void kernel_launch(void* const* d_in, const int* in_sizes, int n_in,
                              void* d_out, int out_size, void* d_ws, size_t ws_size,
                              hipStream_t stream) {
    const float* bits = (const float*)d_in[0];
    char* ws = (char*)d_ws;
    u64*    packed = (u64*)ws;                         // 2 MB
    int*    Cp     = (int*)(ws + (2u << 20));          // 16 slices x 1 MB = 16 MB
    double* lg     = (double*)(ws + (18u << 20));      // 256 KB + 8 B
    double* bsum   = (double*)(ws + (19u << 20));      // 4 KB
    int*    bcnt   = (int*)(ws + (19u << 20) + 8192);  // 2 KB

    pack_kernel<<<256, 256, 0, stream>>>(bits, packed, lg);
    gram_kernel<<<NTILE * NSLICE, 256, 0, stream>>>(packed, Cp);
    mi_kernel<<<NBITS, 256, 0, stream>>>(Cp, lg, bsum, bcnt);
    final_kernel<<<1, 256, 0, stream>>>(bsum, bcnt, (float*)d_out, NBITS);
}